// Round 5
// baseline (48432.187 us; speedup 1.0000x reference)
//
#include <hip/hip_runtime.h>
#include <hip/hip_fp16.h>
#include <math.h>

#define NB   32
#define LD   256
#define LE   258
#define HID  512
#define H3   1536
#define MLP  256
#define NL   4

typedef _Float16 h2 __attribute__((ext_vector_type(2)));

// ---------------- GRU: 32 WGs (one per batch), 1024 threads ----------------
// Thread pair (2u,2u+1) owns hidden unit u: each thread holds the two
// column-halves' f16 weights for all 3 gate rows (3*128 h2 = 384 VGPRs).
// h state fp32 in LDS; sync = __syncthreads only (no atomics, no cross-WG).
__global__ __launch_bounds__(1024)
void k_gru(const float* __restrict__ GI, const float* __restrict__ W_hh,
           const float* __restrict__ b_hh, const float* __restrict__ h0,
           float* __restrict__ dout){
  const int b    = blockIdx.x;
  const int tid  = threadIdx.x;      // 0..1023
  const int r    = tid >> 1;         // hidden unit 0..511
  const int half = tid & 1;          // column half: cols [half*256, half*256+256)
  const int c0   = half << 8;

  __shared__ __align__(16) float h_lds[HID];

  // --- prologue: W_hh[s*512+r][c0..c0+255] -> w[s][0..127] (f16x2, static) ---
  h2 w[3][128];
  #pragma unroll
  for (int s=0;s<3;s++){
    const float4* wr = (const float4*)(W_hh + ((size_t)(s*HID + r))*HID + c0);
    #pragma unroll
    for (int i=0;i<64;i++){
      float4 v = wr[i];
      h2 p0; p0[0]=(_Float16)v.x; p0[1]=(_Float16)v.y;
      h2 p1; p1[0]=(_Float16)v.z; p1[1]=(_Float16)v.w;
      w[s][2*i] = p0; w[s][2*i+1] = p1;
    }
  }
  float bh0 = b_hh[r], bh1 = b_hh[HID + r], bh2 = b_hh[2*HID + r];
  float h_old = h0[(size_t)b*HID + r];
  for (int i=tid; i<HID; i+=1024) h_lds[i] = h0[(size_t)b*HID + i];
  __syncthreads();

  const float* gi_base = GI + (size_t)b*LD*H3;
  float* db = dout + (size_t)b*LD*HID;

  for (int t=0;t<LD;t++){
    // issue GI loads for this step now; consumed ~6000cy later (after the dot)
    const float* g = gi_base + (size_t)t*H3;
    float gi0 = g[r], gi1 = g[HID + r], gi2 = g[2*HID + r];

    // partial dots over this thread's 256-column half (f16 w, fp32 h)
    float a0=0.f, a1=0.f, a2=0.f;
    const float4* hl = (const float4*)(h_lds + c0);
    #pragma unroll
    for (int i=0;i<64;i++){
      float4 hv = hl[i];
      h2 w0, w1;
      w0 = w[0][2*i]; w1 = w[0][2*i+1];
      a0 = fmaf((float)w0[0], hv.x, a0); a0 = fmaf((float)w0[1], hv.y, a0);
      a0 = fmaf((float)w1[0], hv.z, a0); a0 = fmaf((float)w1[1], hv.w, a0);
      w0 = w[1][2*i]; w1 = w[1][2*i+1];
      a1 = fmaf((float)w0[0], hv.x, a1); a1 = fmaf((float)w0[1], hv.y, a1);
      a1 = fmaf((float)w1[0], hv.z, a1); a1 = fmaf((float)w1[1], hv.w, a1);
      w0 = w[2][2*i]; w1 = w[2][2*i+1];
      a2 = fmaf((float)w0[0], hv.x, a2); a2 = fmaf((float)w0[1], hv.y, a2);
      a2 = fmaf((float)w1[0], hv.z, a2); a2 = fmaf((float)w1[1], hv.w, a2);
    }
    // combine the two halves (lane pair)
    a0 += __shfl_xor(a0, 1);
    a1 += __shfl_xor(a1, 1);
    a2 += __shfl_xor(a2, 1);

    // GRU update (computed identically by both threads of the pair)
    float rr = 1.f/(1.f+__expf(-(gi0 + a0 + bh0)));
    float zz = 1.f/(1.f+__expf(-(gi1 + a1 + bh1)));
    float nn = tanhf(gi2 + rr*(a2 + bh2));
    float hnew = (1.f-zz)*nn + zz*h_old;
    h_old = hnew;

    __syncthreads();                       // all reads of old h done
    if (half==0){
      h_lds[r] = hnew;
      db[(size_t)t*HID + r] = hnew;
    }
    __syncthreads();                       // new h visible
  }
}

// ---------- generic NT gemm: C[M,N] = A[M,K] @ B[N,K]^T (+bias)(+relu) ------
template<int BIAS, int RELU>
__global__ __launch_bounds__(256)
void k_gemm_nt(const float* __restrict__ A, const float* __restrict__ Bm,
               const float* __restrict__ bias, float* __restrict__ C,
               int M, int N, int K){
  __shared__ float As[32][68];
  __shared__ float Bs[32][68];
  const int bm = blockIdx.y*64, bn = blockIdx.x*64;
  const int tid = threadIdx.x;
  const int tx = tid & 15, ty = tid >> 4;
  const int lr = tid >> 3;
  const int lk = (tid & 7) << 2;
  const float* A0 = A + (size_t)(bm+lr)*K + lk;
  const float* A1 = A + (size_t)(bm+lr+32)*K + lk;
  const float* B0 = Bm + (size_t)(bn+lr)*K + lk;
  const float* B1 = Bm + (size_t)(bn+lr+32)*K + lk;
  float acc[4][4] = {};
  for (int k0=0;k0<K;k0+=32){
    float4 a0 = *(const float4*)(A0 + k0);
    float4 a1 = *(const float4*)(A1 + k0);
    float4 b0 = *(const float4*)(B0 + k0);
    float4 b1 = *(const float4*)(B1 + k0);
    __syncthreads();
    As[lk+0][lr]=a0.x; As[lk+1][lr]=a0.y; As[lk+2][lr]=a0.z; As[lk+3][lr]=a0.w;
    As[lk+0][lr+32]=a1.x; As[lk+1][lr+32]=a1.y; As[lk+2][lr+32]=a1.z; As[lk+3][lr+32]=a1.w;
    Bs[lk+0][lr]=b0.x; Bs[lk+1][lr]=b0.y; Bs[lk+2][lr]=b0.z; Bs[lk+3][lr]=b0.w;
    Bs[lk+0][lr+32]=b1.x; Bs[lk+1][lr+32]=b1.y; Bs[lk+2][lr+32]=b1.z; Bs[lk+3][lr+32]=b1.w;
    __syncthreads();
    #pragma unroll
    for (int kk=0;kk<32;kk++){
      float4 av = *(const float4*)&As[kk][ty<<2];
      float4 bv = *(const float4*)&Bs[kk][tx<<2];
      float a4[4] = {av.x,av.y,av.z,av.w};
      float b4[4] = {bv.x,bv.y,bv.z,bv.w};
      #pragma unroll
      for (int i=0;i<4;i++)
        #pragma unroll
        for (int j=0;j<4;j++)
          acc[i][j] = fmaf(a4[i], b4[j], acc[i][j]);
    }
  }
  #pragma unroll
  for (int i=0;i<4;i++){
    int m = bm + (ty<<2) + i;
    #pragma unroll
    for (int j=0;j<4;j++){
      int n = bn + (tx<<2) + j;
      float v = acc[i][j];
      if (BIAS) v += bias[n];
      if (RELU) v = fmaxf(v, 0.f);
      C[(size_t)m*N + n] = v;
    }
  }
}

// ---------- NN gemm (batched over l): T[l][b][d][k] = d_h @ U[l] ----------
__global__ __launch_bounds__(256)
void k_gemm_nn_T(const float* __restrict__ A, const float* __restrict__ U,
                 float* __restrict__ T){
  __shared__ float As[32][68];
  __shared__ float Bs[32][68];
  const int l = blockIdx.z;
  const float* Bm = U + (size_t)l*MLP*MLP;
  float* C = T + (size_t)l*NB*LD*MLP;
  const int bm = blockIdx.y*64, bn = blockIdx.x*64;
  const int tid = threadIdx.x;
  const int tx = tid & 15, ty = tid >> 4;
  const int lr = tid >> 3;
  const int lk = (tid & 7) << 2;
  const int bk_r = tid >> 4;
  const int bn_c = (tid & 15) << 2;
  const float* A0 = A + (size_t)(bm+lr)*MLP + lk;
  const float* A1 = A + (size_t)(bm+lr+32)*MLP + lk;
  float acc[4][4] = {};
  for (int k0=0;k0<MLP;k0+=32){
    float4 a0 = *(const float4*)(A0 + k0);
    float4 a1 = *(const float4*)(A1 + k0);
    float4 u0 = *(const float4*)(Bm + (size_t)(k0+bk_r)*MLP + bn + bn_c);
    float4 u1 = *(const float4*)(Bm + (size_t)(k0+bk_r+16)*MLP + bn + bn_c);
    __syncthreads();
    As[lk+0][lr]=a0.x; As[lk+1][lr]=a0.y; As[lk+2][lr]=a0.z; As[lk+3][lr]=a0.w;
    As[lk+0][lr+32]=a1.x; As[lk+1][lr+32]=a1.y; As[lk+2][lr+32]=a1.z; As[lk+3][lr+32]=a1.w;
    *(float4*)&Bs[bk_r][bn_c]    = u0;
    *(float4*)&Bs[bk_r+16][bn_c] = u1;
    __syncthreads();
    #pragma unroll
    for (int kk=0;kk<32;kk++){
      float4 av = *(const float4*)&As[kk][ty<<2];
      float4 bv = *(const float4*)&Bs[kk][tx<<2];
      float a4[4] = {av.x,av.y,av.z,av.w};
      float b4[4] = {bv.x,bv.y,bv.z,bv.w};
      #pragma unroll
      for (int i=0;i<4;i++)
        #pragma unroll
        for (int j=0;j<4;j++)
          acc[i][j] = fmaf(a4[i], b4[j], acc[i][j]);
    }
  }
  #pragma unroll
  for (int i=0;i<4;i++){
    int m = bm + (ty<<2) + i;
    #pragma unroll
    for (int j=0;j<4;j++)
      C[(size_t)m*MLP + bn + (tx<<2) + j] = acc[i][j];
  }
}

// -------- s_e / s_d: S[b][l][r] = dot(W[l], Hm[b,r,:]) --------
__global__ void k_bilinear(const float* __restrict__ W, const float* __restrict__ Hm,
                           float* __restrict__ S, int Lrows){
  int idx = blockIdx.x*256 + threadIdx.x;
  if (idx >= NB*Lrows) return;
  int b = idx / Lrows, r = idx - b*Lrows;
  const float* row = Hm + (size_t)idx*MLP;
  float acc[NL] = {0.f,0.f,0.f,0.f};
  for (int h=0; h<MLP; h+=4){
    float4 x = *(const float4*)(row + h);
    #pragma unroll
    for (int l=0;l<NL;l++){
      float4 w = *(const float4*)(W + l*MLP + h);
      acc[l] += x.x*w.x + x.y*w.y + x.z*w.z + x.w*w.w;
    }
  }
  #pragma unroll
  for (int l=0;l<NL;l++) S[((size_t)b*NL + l)*Lrows + r] = acc[l];
}

// -------- final: out[b,d,e,l] = T[l,b,d,:]·e_h[b,e,:] + s_d + s_e + b_aff --------
__global__ __launch_bounds__(256)
void k_s2(const float* __restrict__ T, const float* __restrict__ eh,
          const float* __restrict__ sd, const float* __restrict__ se,
          const float* __restrict__ baff, float* __restrict__ out){
  __shared__ float As[32][68];
  __shared__ float Bs[32][68];
  const int b = blockIdx.z;
  const int d0 = blockIdx.y*64, e0 = blockIdx.x*64;
  const int tid = threadIdx.x;
  const int tx = tid & 15, ty = tid >> 4;
  const int lr = tid >> 3;
  const int lk = (tid & 7) << 2;
  const float* EH = eh + (size_t)b*LE*MLP;
  for (int l=0;l<NL;l++){
    const float* A = T + ((size_t)(l*NB + b))*LD*MLP;
    float acc[4][4] = {};
    for (int k0=0;k0<MLP;k0+=32){
      float4 a0 = *(const float4*)(A + (size_t)(d0+lr)*MLP + k0 + lk);
      float4 a1 = *(const float4*)(A + (size_t)(d0+lr+32)*MLP + k0 + lk);
      float4 z4 = make_float4(0.f,0.f,0.f,0.f);
      int er0 = e0+lr, er1 = e0+lr+32;
      float4 b0 = (er0<LE) ? *(const float4*)(EH + (size_t)er0*MLP + k0 + lk) : z4;
      float4 b1 = (er1<LE) ? *(const float4*)(EH + (size_t)er1*MLP + k0 + lk) : z4;
      __syncthreads();
      As[lk+0][lr]=a0.x; As[lk+1][lr]=a0.y; As[lk+2][lr]=a0.z; As[lk+3][lr]=a0.w;
      As[lk+0][lr+32]=a1.x; As[lk+1][lr+32]=a1.y; As[lk+2][lr+32]=a1.z; As[lk+3][lr+32]=a1.w;
      Bs[lk+0][lr]=b0.x; Bs[lk+1][lr]=b0.y; Bs[lk+2][lr]=b0.z; Bs[lk+3][lr]=b0.w;
      Bs[lk+0][lr+32]=b1.x; Bs[lk+1][lr+32]=b1.y; Bs[lk+2][lr+32]=b1.z; Bs[lk+3][lr+32]=b1.w;
      __syncthreads();
      #pragma unroll
      for (int kk=0;kk<32;kk++){
        float4 av = *(const float4*)&As[kk][ty<<2];
        float4 bv = *(const float4*)&Bs[kk][tx<<2];
        float a4[4] = {av.x,av.y,av.z,av.w};
        float b4[4] = {bv.x,bv.y,bv.z,bv.w};
        #pragma unroll
        for (int i=0;i<4;i++)
          #pragma unroll
          for (int j=0;j<4;j++)
            acc[i][j] = fmaf(a4[i], b4[j], acc[i][j]);
      }
    }
    float bl = baff[l];
    float sdl[4], sel[4];
    #pragma unroll
    for (int i=0;i<4;i++) sdl[i] = sd[((size_t)b*NL + l)*LD + d0 + (ty<<2) + i];
    #pragma unroll
    for (int j=0;j<4;j++){
      int e = e0 + (tx<<2) + j;
      sel[j] = (e<LE) ? se[((size_t)b*NL + l)*LE + e] : 0.f;
    }
    #pragma unroll
    for (int i=0;i<4;i++){
      int d = d0 + (ty<<2) + i;
      #pragma unroll
      for (int j=0;j<4;j++){
        int e = e0 + (tx<<2) + j;
        if (e < LE)
          out[(((size_t)b*LD + d)*LE + e)*NL + l] = acc[i][j] + sdl[i] + sel[j] + bl;
      }
    }
  }
}

extern "C" void kernel_launch(void* const* d_in, const int* in_sizes, int n_in,
                              void* d_out, int out_size, void* d_ws, size_t ws_size,
                              hipStream_t stream){
  const float* e_outputs = (const float*)d_in[0];
  const float* d_inputs  = (const float*)d_in[1];
  const float* h0        = (const float*)d_in[2];
  const float* W_ih      = (const float*)d_in[3];
  const float* W_hh      = (const float*)d_in[4];
  const float* b_ih      = (const float*)d_in[5];
  const float* b_hh      = (const float*)d_in[6];
  const float* e_mlp_w   = (const float*)d_in[7];
  const float* e_mlp_b   = (const float*)d_in[8];
  const float* d_mlp_w   = (const float*)d_in[9];
  const float* d_mlp_b   = (const float*)d_in[10];
  const float* W_e       = (const float*)d_in[11];
  const float* W_d       = (const float*)d_in[12];
  const float* U         = (const float*)d_in[13];
  const float* b_aff     = (const float*)d_in[14];
  float* out = (float*)d_out;
  float* ws  = (float*)d_ws;

  // workspace layout (floats). T reuses GI's region (GI dead after k_gru).
  float* GI   = ws;                        // 32*256*1536 = 12,582,912
  float* T    = ws;                        // 4*32*256*256 = 8,388,608 (overlaps GI)
  float* dout = ws   + 12582912 + 786432;  // 32*256*512 = 4,194,304
  float* eh   = dout + 4194304;            // 32*258*256 = 2,113,536
  float* dh   = eh   + 2113536;            // 32*256*256 = 2,097,152
  float* se   = dh   + 2097152;            // 32*4*258 = 33,024
  float* sd   = se   + 33024;              // 32*4*256 = 32,768

  // GI = d_inputs @ W_ih^T + b_ih   (M=8192,N=1536,K=512)
  k_gemm_nt<1,0><<<dim3(H3/64, (NB*LD)/64), 256, 0, stream>>>(d_inputs, W_ih, b_ih, GI, NB*LD, H3, HID);
  // e_h = relu(e_outputs @ e_mlp_w^T + b)  (M=8256,N=256,K=512)
  k_gemm_nt<1,1><<<dim3(MLP/64, (NB*LE)/64), 256, 0, stream>>>(e_outputs, e_mlp_w, e_mlp_b, eh, NB*LE, MLP, HID);
  // GRU recurrence -> d_outputs (one WG per batch, weights in VGPRs, no atomics)
  k_gru<<<dim3(NB), 1024, 0, stream>>>(GI, W_hh, b_hh, h0, dout);
  // d_h = relu(d_outputs @ d_mlp_w^T + b)  (M=8192,N=256,K=512)
  k_gemm_nt<1,1><<<dim3(MLP/64, (NB*LD)/64), 256, 0, stream>>>(dout, d_mlp_w, d_mlp_b, dh, NB*LD, MLP, HID);
  // T[l] = d_h @ U[l]  (M=8192,N=256,K=256, batched over l)
  k_gemm_nn_T<<<dim3(MLP/64, (NB*LD)/64, NL), 256, 0, stream>>>(dh, U, T);
  // s_e, s_d
  k_bilinear<<<dim3((NB*LE+255)/256), 256, 0, stream>>>(W_e, eh, se, LE);
  k_bilinear<<<dim3((NB*LD+255)/256), 256, 0, stream>>>(W_d, dh, sd, LD);
  // out[b,d,e,l] = T[l,b,d,:]·e_h[b,e,:] + s_d + s_e + b_aff
  k_s2<<<dim3(5, LD/64, NB), 256, 0, stream>>>(T, eh, sd, se, b_aff, out);
}

// Round 6
// 2800.851 us; speedup vs baseline: 17.2920x; 17.2920x over previous
//
#include <hip/hip_runtime.h>
#include <hip/hip_fp16.h>
#include <math.h>

#define NB   32
#define LD   256
#define LE   258
#define HID  512
#define H3   1536
#define MLP  256
#define NL   4
#define FLAG_STRIDE 32   // u32s -> 128 B per flag line

typedef _Float16 h2 __attribute__((ext_vector_type(2)));

// ---------- init: zero per-(batch,slice) flags (every launch, graph-safe) ----------
__global__ void k_init(uint32_t* __restrict__ flags){
  for (int i = threadIdx.x; i < NB*8*FLAG_STRIDE; i += 256) flags[i] = 0u;
}

// ---------------- GRU: 256 WGs = 32 batches x 8 slices ----------------
// 192 threads/WG, 1 gate-row per thread, weights f16x2 register-resident
// (256 VGPRs, verified no-spill at 192thr/1-wave-per-SIMD). h fp32.
// Sync: ALL-RELAXED sc1 protocol -- no acquire/release cache maintenance.
//   writer: relaxed payload stores -> s_waitcnt vmcnt(0) -> relaxed flag store
//   reader: wave-1 relaxed poll -> __syncthreads -> relaxed payload reload
__global__ __launch_bounds__(192,1)
void k_gru(const float* __restrict__ GI, const float* __restrict__ W_hh,
           const float* __restrict__ b_hh, const float* __restrict__ h0,
           float* __restrict__ dout, float* __restrict__ hbuf,   // 2*NB*HID f32
           uint32_t* __restrict__ flags){
  const int wg  = blockIdx.x;
  const int b   = wg >> 3, g = wg & 7;
  const int tid = threadIdx.x;
  const int sect = tid >> 6;                  // 0=r, 1=z, 2=n
  const int u    = tid & 63;
  const int c    = sect*HID + g*64 + u;       // gate row in [0,1536)

  __shared__ __align__(16) float h_lds[HID];
  __shared__ float zs[64], gs[64], ns[64];

  // --- prologue: W_hh[c][:] -> 256 f16x2 VGPRs (one-time, static indexing) ---
  h2 w[256];
  const float4* wr = (const float4*)(W_hh + (size_t)c*HID);
  #pragma unroll
  for (int i=0;i<128;i++){
    float4 v = wr[i];
    h2 p0; p0[0]=(_Float16)v.x; p0[1]=(_Float16)v.y;
    h2 p1; p1[0]=(_Float16)v.z; p1[1]=(_Float16)v.w;
    w[2*i] = p0; w[2*i+1] = p1;
  }
  const float bh = b_hh[c];
  float h_old = (tid < 64) ? h0[(size_t)b*HID + g*64 + u] : 0.f;
  const float* gi_base = GI + (size_t)b*LD*H3 + c;
  uint32_t* fb = flags + (size_t)b*8*FLAG_STRIDE;   // 8 padded flags for batch b
  float* db = dout + (size_t)b*LD*HID + g*64;

  // initial h_0 straight from h0 (fp32)
  for (int i=tid;i<HID;i+=192) h_lds[i] = h0[(size_t)b*HID + i];
  __syncthreads();

  float gi = gi_base[0];                      // GI for step 0
  for (int t=0;t<LD;t++){
    // gh[c] = sum_k W_hh[c][k] * h[k]  (f16 weight, fp32 h, 4 indep accums)
    float a0=0.f, a1=0.f, a2=0.f, a3=0.f;
    const float4* hl = (const float4*)h_lds;
    #pragma unroll
    for (int kk=0;kk<128;kk++){
      float4 hv = hl[kk];
      h2 w0 = w[2*kk], w1 = w[2*kk+1];
      a0 = fmaf((float)w0[0], hv.x, a0);
      a1 = fmaf((float)w0[1], hv.y, a1);
      a2 = fmaf((float)w1[0], hv.z, a2);
      a3 = fmaf((float)w1[1], hv.w, a3);
    }
    float hh = (a0+a1) + (a2+a3) + bh;
    if (sect==1)      zs[u] = gi + hh;
    else if (sect==2){ gs[u] = gi; ns[u] = hh; }
    float pre_r = gi + hh;                     // valid for sect==0
    __syncthreads();
    float hnew = 0.f;
    if (tid < 64){
      float r = __builtin_amdgcn_rcpf(1.f + __expf(-pre_r));
      float z = __builtin_amdgcn_rcpf(1.f + __expf(-zs[u]));
      float x = gs[u] + r*ns[u];
      float e2 = __expf(2.f*x);
      float n = 1.f - 2.f*__builtin_amdgcn_rcpf(e2 + 1.f);   // tanh(x), robust
      hnew = (1.f-z)*n + z*h_old;
      h_old = hnew;
    }
    if (t < LD-1){
      float* hb = hbuf + (size_t)((t+1)&1)*(NB*HID) + (size_t)b*HID;
      if (tid < 64){
        // payload (relaxed, sc1 -> LLC), then wave-wide completion, then flag
        __hip_atomic_store(hb + g*64 + u, hnew,
                           __ATOMIC_RELAXED, __HIP_MEMORY_SCOPE_AGENT);
        asm volatile("s_waitcnt vmcnt(0)" ::: "memory");
        if (tid == 0)
          __hip_atomic_store(fb + g*FLAG_STRIDE, (uint32_t)(t+1),
                             __ATOMIC_RELAXED, __HIP_MEMORY_SCOPE_AGENT);
        // non-critical stores/loads AFTER the flag: don't delay visibility
        db[(size_t)t*HID + u] = hnew;
      }
      gi = gi_base[(size_t)(t+1)*H3];          // prefetch next-step GI
      if (tid >= 64 && tid < 72){              // wave 1 polls (overlaps wave 0)
        int s = tid - 64;
        int guard = 0;
        while (__hip_atomic_load(fb + s*FLAG_STRIDE, __ATOMIC_RELAXED,
                                 __HIP_MEMORY_SCOPE_AGENT) < (uint32_t)(t+1)
               && guard < (1<<20)){ __builtin_amdgcn_s_sleep(1); ++guard; }
      }
      __syncthreads();
      for (int i=tid;i<HID;i+=192)
        h_lds[i] = __hip_atomic_load(hb+i, __ATOMIC_RELAXED, __HIP_MEMORY_SCOPE_AGENT);
      __syncthreads();
    } else {
      if (tid < 64) db[(size_t)t*HID + u] = hnew;
    }
  }
}

// ---------- generic NT gemm: C[M,N] = A[M,K] @ B[N,K]^T (+bias)(+relu) ------
template<int BIAS, int RELU>
__global__ __launch_bounds__(256)
void k_gemm_nt(const float* __restrict__ A, const float* __restrict__ Bm,
               const float* __restrict__ bias, float* __restrict__ C,
               int M, int N, int K){
  __shared__ float As[32][68];
  __shared__ float Bs[32][68];
  const int bm = blockIdx.y*64, bn = blockIdx.x*64;
  const int tid = threadIdx.x;
  const int tx = tid & 15, ty = tid >> 4;
  const int lr = tid >> 3;
  const int lk = (tid & 7) << 2;
  const float* A0 = A + (size_t)(bm+lr)*K + lk;
  const float* A1 = A + (size_t)(bm+lr+32)*K + lk;
  const float* B0 = Bm + (size_t)(bn+lr)*K + lk;
  const float* B1 = Bm + (size_t)(bn+lr+32)*K + lk;
  float acc[4][4] = {};
  for (int k0=0;k0<K;k0+=32){
    float4 a0 = *(const float4*)(A0 + k0);
    float4 a1 = *(const float4*)(A1 + k0);
    float4 b0 = *(const float4*)(B0 + k0);
    float4 b1 = *(const float4*)(B1 + k0);
    __syncthreads();
    As[lk+0][lr]=a0.x; As[lk+1][lr]=a0.y; As[lk+2][lr]=a0.z; As[lk+3][lr]=a0.w;
    As[lk+0][lr+32]=a1.x; As[lk+1][lr+32]=a1.y; As[lk+2][lr+32]=a1.z; As[lk+3][lr+32]=a1.w;
    Bs[lk+0][lr]=b0.x; Bs[lk+1][lr]=b0.y; Bs[lk+2][lr]=b0.z; Bs[lk+3][lr]=b0.w;
    Bs[lk+0][lr+32]=b1.x; Bs[lk+1][lr+32]=b1.y; Bs[lk+2][lr+32]=b1.z; Bs[lk+3][lr+32]=b1.w;
    __syncthreads();
    #pragma unroll
    for (int kk=0;kk<32;kk++){
      float4 av = *(const float4*)&As[kk][ty<<2];
      float4 bv = *(const float4*)&Bs[kk][tx<<2];
      float a4[4] = {av.x,av.y,av.z,av.w};
      float b4[4] = {bv.x,bv.y,bv.z,bv.w};
      #pragma unroll
      for (int i=0;i<4;i++)
        #pragma unroll
        for (int j=0;j<4;j++)
          acc[i][j] = fmaf(a4[i], b4[j], acc[i][j]);
    }
  }
  #pragma unroll
  for (int i=0;i<4;i++){
    int m = bm + (ty<<2) + i;
    #pragma unroll
    for (int j=0;j<4;j++){
      int n = bn + (tx<<2) + j;
      float v = acc[i][j];
      if (BIAS) v += bias[n];
      if (RELU) v = fmaxf(v, 0.f);
      C[(size_t)m*N + n] = v;
    }
  }
}

// ---------- NN gemm (batched over l): T[l][b][d][k] = d_h @ U[l] ----------
__global__ __launch_bounds__(256)
void k_gemm_nn_T(const float* __restrict__ A, const float* __restrict__ U,
                 float* __restrict__ T){
  __shared__ float As[32][68];
  __shared__ float Bs[32][68];
  const int l = blockIdx.z;
  const float* Bm = U + (size_t)l*MLP*MLP;
  float* C = T + (size_t)l*NB*LD*MLP;
  const int bm = blockIdx.y*64, bn = blockIdx.x*64;
  const int tid = threadIdx.x;
  const int tx = tid & 15, ty = tid >> 4;
  const int lr = tid >> 3;
  const int lk = (tid & 7) << 2;
  const int bk_r = tid >> 4;
  const int bn_c = (tid & 15) << 2;
  const float* A0 = A + (size_t)(bm+lr)*MLP + lk;
  const float* A1 = A + (size_t)(bm+lr+32)*MLP + lk;
  float acc[4][4] = {};
  for (int k0=0;k0<MLP;k0+=32){
    float4 a0 = *(const float4*)(A0 + k0);
    float4 a1 = *(const float4*)(A1 + k0);
    float4 u0 = *(const float4*)(Bm + (size_t)(k0+bk_r)*MLP + bn + bn_c);
    float4 u1 = *(const float4*)(Bm + (size_t)(k0+bk_r+16)*MLP + bn + bn_c);
    __syncthreads();
    As[lk+0][lr]=a0.x; As[lk+1][lr]=a0.y; As[lk+2][lr]=a0.z; As[lk+3][lr]=a0.w;
    As[lk+0][lr+32]=a1.x; As[lk+1][lr+32]=a1.y; As[lk+2][lr+32]=a1.z; As[lk+3][lr+32]=a1.w;
    *(float4*)&Bs[bk_r][bn_c]    = u0;
    *(float4*)&Bs[bk_r+16][bn_c] = u1;
    __syncthreads();
    #pragma unroll
    for (int kk=0;kk<32;kk++){
      float4 av = *(const float4*)&As[kk][ty<<2];
      float4 bv = *(const float4*)&Bs[kk][tx<<2];
      float a4[4] = {av.x,av.y,av.z,av.w};
      float b4[4] = {bv.x,bv.y,bv.z,bv.w};
      #pragma unroll
      for (int i=0;i<4;i++)
        #pragma unroll
        for (int j=0;j<4;j++)
          acc[i][j] = fmaf(a4[i], b4[j], acc[i][j]);
    }
  }
  #pragma unroll
  for (int i=0;i<4;i++){
    int m = bm + (ty<<2) + i;
    #pragma unroll
    for (int j=0;j<4;j++)
      C[(size_t)m*MLP + bn + (tx<<2) + j] = acc[i][j];
  }
}

// -------- s_e / s_d: S[b][l][r] = dot(W[l], Hm[b,r,:]) --------
__global__ void k_bilinear(const float* __restrict__ W, const float* __restrict__ Hm,
                           float* __restrict__ S, int Lrows){
  int idx = blockIdx.x*256 + threadIdx.x;
  if (idx >= NB*Lrows) return;
  int b = idx / Lrows, r = idx - b*Lrows;
  const float* row = Hm + (size_t)idx*MLP;
  float acc[NL] = {0.f,0.f,0.f,0.f};
  for (int h=0; h<MLP; h+=4){
    float4 x = *(const float4*)(row + h);
    #pragma unroll
    for (int l=0;l<NL;l++){
      float4 w = *(const float4*)(W + l*MLP + h);
      acc[l] += x.x*w.x + x.y*w.y + x.z*w.z + x.w*w.w;
    }
  }
  #pragma unroll
  for (int l=0;l<NL;l++) S[((size_t)b*NL + l)*Lrows + r] = acc[l];
}

// -------- final: out[b,d,e,l] = T[l,b,d,:]·e_h[b,e,:] + s_d + s_e + b_aff --------
__global__ __launch_bounds__(256)
void k_s2(const float* __restrict__ T, const float* __restrict__ eh,
          const float* __restrict__ sd, const float* __restrict__ se,
          const float* __restrict__ baff, float* __restrict__ out){
  __shared__ float As[32][68];
  __shared__ float Bs[32][68];
  const int b = blockIdx.z;
  const int d0 = blockIdx.y*64, e0 = blockIdx.x*64;
  const int tid = threadIdx.x;
  const int tx = tid & 15, ty = tid >> 4;
  const int lr = tid >> 3;
  const int lk = (tid & 7) << 2;
  const float* EH = eh + (size_t)b*LE*MLP;
  for (int l=0;l<NL;l++){
    const float* A = T + ((size_t)(l*NB + b))*LD*MLP;
    float acc[4][4] = {};
    for (int k0=0;k0<MLP;k0+=32){
      float4 a0 = *(const float4*)(A + (size_t)(d0+lr)*MLP + k0 + lk);
      float4 a1 = *(const float4*)(A + (size_t)(d0+lr+32)*MLP + k0 + lk);
      float4 z4 = make_float4(0.f,0.f,0.f,0.f);
      int er0 = e0+lr, er1 = e0+lr+32;
      float4 b0 = (er0<LE) ? *(const float4*)(EH + (size_t)er0*MLP + k0 + lk) : z4;
      float4 b1 = (er1<LE) ? *(const float4*)(EH + (size_t)er1*MLP + k0 + lk) : z4;
      __syncthreads();
      As[lk+0][lr]=a0.x; As[lk+1][lr]=a0.y; As[lk+2][lr]=a0.z; As[lk+3][lr]=a0.w;
      As[lk+0][lr+32]=a1.x; As[lk+1][lr+32]=a1.y; As[lk+2][lr+32]=a1.z; As[lk+3][lr+32]=a1.w;
      Bs[lk+0][lr]=b0.x; Bs[lk+1][lr]=b0.y; Bs[lk+2][lr]=b0.z; Bs[lk+3][lr]=b0.w;
      Bs[lk+0][lr+32]=b1.x; Bs[lk+1][lr+32]=b1.y; Bs[lk+2][lr+32]=b1.z; Bs[lk+3][lr+32]=b1.w;
      __syncthreads();
      #pragma unroll
      for (int kk=0;kk<32;kk++){
        float4 av = *(const float4*)&As[kk][ty<<2];
        float4 bv = *(const float4*)&Bs[kk][tx<<2];
        float a4[4] = {av.x,av.y,av.z,av.w};
        float b4[4] = {bv.x,bv.y,bv.z,bv.w};
        #pragma unroll
        for (int i=0;i<4;i++)
          #pragma unroll
          for (int j=0;j<4;j++)
            acc[i][j] = fmaf(a4[i], b4[j], acc[i][j]);
      }
    }
    float bl = baff[l];
    float sdl[4], sel[4];
    #pragma unroll
    for (int i=0;i<4;i++) sdl[i] = sd[((size_t)b*NL + l)*LD + d0 + (ty<<2) + i];
    #pragma unroll
    for (int j=0;j<4;j++){
      int e = e0 + (tx<<2) + j;
      sel[j] = (e<LE) ? se[((size_t)b*NL + l)*LE + e] : 0.f;
    }
    #pragma unroll
    for (int i=0;i<4;i++){
      int d = d0 + (ty<<2) + i;
      #pragma unroll
      for (int j=0;j<4;j++){
        int e = e0 + (tx<<2) + j;
        if (e < LE)
          out[(((size_t)b*LD + d)*LE + e)*NL + l] = acc[i][j] + sdl[i] + sel[j] + bl;
      }
    }
  }
}

extern "C" void kernel_launch(void* const* d_in, const int* in_sizes, int n_in,
                              void* d_out, int out_size, void* d_ws, size_t ws_size,
                              hipStream_t stream){
  const float* e_outputs = (const float*)d_in[0];
  const float* d_inputs  = (const float*)d_in[1];
  const float* h0        = (const float*)d_in[2];
  const float* W_ih      = (const float*)d_in[3];
  const float* W_hh      = (const float*)d_in[4];
  const float* b_ih      = (const float*)d_in[5];
  const float* b_hh      = (const float*)d_in[6];
  const float* e_mlp_w   = (const float*)d_in[7];
  const float* e_mlp_b   = (const float*)d_in[8];
  const float* d_mlp_w   = (const float*)d_in[9];
  const float* d_mlp_b   = (const float*)d_in[10];
  const float* W_e       = (const float*)d_in[11];
  const float* W_d       = (const float*)d_in[12];
  const float* U         = (const float*)d_in[13];
  const float* b_aff     = (const float*)d_in[14];
  float* out = (float*)d_out;
  float* ws  = (float*)d_ws;

  // workspace layout (floats). T reuses GI's region (GI dead after k_gru).
  float* GI   = ws;                        // 32*256*1536 = 12,582,912
  float* T    = ws;                        // 4*32*256*256 = 8,388,608 (overlaps GI)
  float* hbuf = ws + 12582912;             // 2*32*512 = 32,768 f32 (double buffer)
  uint32_t* flags = (uint32_t*)(hbuf + 2*NB*HID);  // 32*8*32 u32 = 8192
  float* dout = ws   + 12582912 + 786432;  // 32*256*512 = 4,194,304
  float* eh   = dout + 4194304;            // 32*258*256 = 2,113,536
  float* dh   = eh   + 2113536;            // 32*256*256 = 2,097,152
  float* se   = dh   + 2097152;            // 32*4*258 = 33,024
  float* sd   = se   + 33024;              // 32*4*256 = 32,768

  k_init<<<dim3(1), 256, 0, stream>>>(flags);
  // GI = d_inputs @ W_ih^T + b_ih   (M=8192,N=1536,K=512)
  k_gemm_nt<1,0><<<dim3(H3/64, (NB*LD)/64), 256, 0, stream>>>(d_inputs, W_ih, b_ih, GI, NB*LD, H3, HID);
  // e_h = relu(e_outputs @ e_mlp_w^T + b)  (M=8256,N=256,K=512)
  k_gemm_nt<1,1><<<dim3(MLP/64, (NB*LE)/64), 256, 0, stream>>>(e_outputs, e_mlp_w, e_mlp_b, eh, NB*LE, MLP, HID);
  // GRU recurrence -> d_outputs (8 slices/batch, f16 weights in VGPRs, fp32 h)
  k_gru<<<dim3(NB*8), 192, 0, stream>>>(GI, W_hh, b_hh, h0, dout, hbuf, flags);
  // d_h = relu(d_outputs @ d_mlp_w^T + b)  (M=8192,N=256,K=512)
  k_gemm_nt<1,1><<<dim3(MLP/64, (NB*LD)/64), 256, 0, stream>>>(dout, d_mlp_w, d_mlp_b, dh, NB*LD, MLP, HID);
  // T[l] = d_h @ U[l]  (M=8192,N=256,K=256, batched over l)
  k_gemm_nn_T<<<dim3(MLP/64, (NB*LD)/64, NL), 256, 0, stream>>>(dh, U, T);
  // s_e, s_d
  k_bilinear<<<dim3((NB*LE+255)/256), 256, 0, stream>>>(W_e, eh, se, LE);
  k_bilinear<<<dim3((NB*LD+255)/256), 256, 0, stream>>>(W_d, dh, sd, LD);
  // out[b,d,e,l] = T[l,b,d,:]·e_h[b,e,:] + s_d + s_e + b_aff
  k_s2<<<dim3(5, LD/64, NB), 256, 0, stream>>>(T, eh, sd, se, b_aff, out);
}

// Round 7
// 2518.427 us; speedup vs baseline: 19.2311x; 1.1121x over previous
//
#include <hip/hip_runtime.h>
#include <hip/hip_fp16.h>
#include <math.h>

#define NB   32
#define LD   256
#define LE   258
#define HID  512
#define H3   1536
#define MLP  256
#define NL   4

typedef _Float16 h2 __attribute__((ext_vector_type(2)));

// ---------- init: zero hbuf tags (every launch, graph-safe, deterministic) ----------
__global__ void k_init(uint32_t* __restrict__ hbuf){
  int i = blockIdx.x*256 + threadIdx.x;
  if (i < 2*NB*HID) hbuf[i] = 0u;   // tag 0: first polls want 1,2 -> no collision
}

// ---------------- GRU: 256 WGs = 32 batches x 8 slices ----------------
// 192 threads/WG, 1 gate-row per thread, weights f16x2 register-resident
// (256 VGPRs). h fp32, transported with a 3-bit step tag embedded in the
// LSBs of each word (<=7ulp). Readers poll the payload itself: no flags,
// no vmcnt drain, no separate reload leg. Two __syncthreads per step.
__global__ __launch_bounds__(192,1)
void k_gru(const float* __restrict__ GI, const float* __restrict__ W_hh,
           const float* __restrict__ b_hh, const float* __restrict__ h0,
           float* __restrict__ dout, float* __restrict__ hbuf){  // 2*NB*HID f32
  const int wg  = blockIdx.x;
  const int b   = wg >> 3, g = wg & 7;
  const int tid = threadIdx.x;
  const int sect = tid >> 6;                  // 0=r, 1=z, 2=n
  const int u    = tid & 63;
  const int c    = sect*HID + g*64 + u;       // gate row in [0,1536)

  __shared__ __align__(16) float h_lds[HID];
  __shared__ float zs[64], gs[64], ns[64];

  // --- prologue: W_hh[c][:] -> 256 f16x2 VGPRs (one-time, static indexing) ---
  h2 w[256];
  const float4* wr = (const float4*)(W_hh + (size_t)c*HID);
  #pragma unroll
  for (int i=0;i<128;i++){
    float4 v = wr[i];
    h2 p0; p0[0]=(_Float16)v.x; p0[1]=(_Float16)v.y;
    h2 p1; p1[0]=(_Float16)v.z; p1[1]=(_Float16)v.w;
    w[2*i] = p0; w[2*i+1] = p1;
  }
  const float bh = b_hh[c];
  float h_old = (tid < 64) ? h0[(size_t)b*HID + g*64 + u] : 0.f;
  const float* gi_base = GI + (size_t)b*LD*H3 + c;
  float* db = dout + (size_t)b*LD*HID + g*64;

  // reader word set: tid, tid+192, tid+384 (last only for tid<128)
  const int w0 = tid, w1 = tid + 192, w2 = tid + 384;

  // initial h_0 straight from h0 (fp32, plain loads)
  for (int i=tid;i<HID;i+=192) h_lds[i] = h0[(size_t)b*HID + i];
  __syncthreads();

  float gi = gi_base[0];                      // GI for step 0
  for (int t=0;t<LD;t++){
    // gh[c] = sum_k W_hh[c][k] * h[k]  (f16 weight, fp32 h, 4 indep accums)
    float a0=0.f, a1=0.f, a2=0.f, a3=0.f;
    const float4* hl = (const float4*)h_lds;
    #pragma unroll
    for (int kk=0;kk<128;kk++){
      float4 hv = hl[kk];
      h2 q0 = w[2*kk], q1 = w[2*kk+1];
      a0 = fmaf((float)q0[0], hv.x, a0);
      a1 = fmaf((float)q0[1], hv.y, a1);
      a2 = fmaf((float)q1[0], hv.z, a2);
      a3 = fmaf((float)q1[1], hv.w, a3);
    }
    float hh = (a0+a1) + (a2+a3) + bh;
    if (sect==1)      zs[u] = gi + hh;
    else if (sect==2){ gs[u] = gi; ns[u] = hh; }
    float pre_r = gi + hh;                     // valid for sect==0
    __syncthreads();                           // SYNC1: all dots done, zs/gs/ns ready

    if (t < LD-1){
      float gnext = gi_base[(size_t)(t+1)*H3]; // prefetch next-step GI (all threads)
      uint32_t* hb = (uint32_t*)(hbuf + (size_t)((t+1)&1)*(NB*HID) + (size_t)b*HID);
      const uint32_t want = (uint32_t)(t+1) & 7u;
      if (tid < 64){
        float r = __builtin_amdgcn_rcpf(1.f + __expf(-pre_r));
        float z = __builtin_amdgcn_rcpf(1.f + __expf(-zs[u]));
        float x = gs[u] + r*ns[u];
        float e2 = __expf(2.f*x);
        float n = 1.f - 2.f*__builtin_amdgcn_rcpf(e2 + 1.f);   // tanh
        float hnew = (1.f-z)*n + z*h_old;
        h_old = hnew;
        uint32_t wb = (__builtin_bit_cast(uint32_t, hnew) & ~7u) | want;
        __hip_atomic_store(hb + g*64 + u, wb,
                           __ATOMIC_RELAXED, __HIP_MEMORY_SCOPE_AGENT);
        db[(size_t)t*HID + u] = hnew;          // off critical path
      }
      // poll the payload itself (tag check), write straight to LDS
      uint32_t* hlu = (uint32_t*)h_lds;
      bool ok = false; int guard = 0;
      while (!ok && guard < (1<<17)){
        uint32_t x0 = __hip_atomic_load(hb+w0, __ATOMIC_RELAXED, __HIP_MEMORY_SCOPE_AGENT);
        uint32_t x1 = __hip_atomic_load(hb+w1, __ATOMIC_RELAXED, __HIP_MEMORY_SCOPE_AGENT);
        uint32_t x2 = want;
        if (w2 < HID)
          x2 = __hip_atomic_load(hb+w2, __ATOMIC_RELAXED, __HIP_MEMORY_SCOPE_AGENT);
        hlu[w0] = x0; hlu[w1] = x1;
        if (w2 < HID) hlu[w2] = x2;
        ok = ((x0&7u)==want) & ((x1&7u)==want) & ((x2&7u)==want);
        if (!ok){ ++guard; __builtin_amdgcn_s_sleep(1); }
      }
      __syncthreads();                         // SYNC2: h_lds fully fresh
      gi = gnext;
    } else {
      if (tid < 64){
        float r = __builtin_amdgcn_rcpf(1.f + __expf(-pre_r));
        float z = __builtin_amdgcn_rcpf(1.f + __expf(-zs[u]));
        float x = gs[u] + r*ns[u];
        float e2 = __expf(2.f*x);
        float n = 1.f - 2.f*__builtin_amdgcn_rcpf(e2 + 1.f);
        float hnew = (1.f-z)*n + z*h_old;
        db[(size_t)t*HID + u] = hnew;
      }
    }
  }
}

// ---------- generic NT gemm: C[M,N] = A[M,K] @ B[N,K]^T (+bias)(+relu) ------
template<int BIAS, int RELU>
__global__ __launch_bounds__(256)
void k_gemm_nt(const float* __restrict__ A, const float* __restrict__ Bm,
               const float* __restrict__ bias, float* __restrict__ C,
               int M, int N, int K){
  __shared__ float As[32][68];
  __shared__ float Bs[32][68];
  const int bm = blockIdx.y*64, bn = blockIdx.x*64;
  const int tid = threadIdx.x;
  const int tx = tid & 15, ty = tid >> 4;
  const int lr = tid >> 3;
  const int lk = (tid & 7) << 2;
  const float* A0 = A + (size_t)(bm+lr)*K + lk;
  const float* A1 = A + (size_t)(bm+lr+32)*K + lk;
  const float* B0 = Bm + (size_t)(bn+lr)*K + lk;
  const float* B1 = Bm + (size_t)(bn+lr+32)*K + lk;
  float acc[4][4] = {};
  for (int k0=0;k0<K;k0+=32){
    float4 a0 = *(const float4*)(A0 + k0);
    float4 a1 = *(const float4*)(A1 + k0);
    float4 b0 = *(const float4*)(B0 + k0);
    float4 b1 = *(const float4*)(B1 + k0);
    __syncthreads();
    As[lk+0][lr]=a0.x; As[lk+1][lr]=a0.y; As[lk+2][lr]=a0.z; As[lk+3][lr]=a0.w;
    As[lk+0][lr+32]=a1.x; As[lk+1][lr+32]=a1.y; As[lk+2][lr+32]=a1.z; As[lk+3][lr+32]=a1.w;
    Bs[lk+0][lr]=b0.x; Bs[lk+1][lr]=b0.y; Bs[lk+2][lr]=b0.z; Bs[lk+3][lr]=b0.w;
    Bs[lk+0][lr+32]=b1.x; Bs[lk+1][lr+32]=b1.y; Bs[lk+2][lr+32]=b1.z; Bs[lk+3][lr+32]=b1.w;
    __syncthreads();
    #pragma unroll
    for (int kk=0;kk<32;kk++){
      float4 av = *(const float4*)&As[kk][ty<<2];
      float4 bv = *(const float4*)&Bs[kk][tx<<2];
      float a4[4] = {av.x,av.y,av.z,av.w};
      float b4[4] = {bv.x,bv.y,bv.z,bv.w};
      #pragma unroll
      for (int i=0;i<4;i++)
        #pragma unroll
        for (int j=0;j<4;j++)
          acc[i][j] = fmaf(a4[i], b4[j], acc[i][j]);
    }
  }
  #pragma unroll
  for (int i=0;i<4;i++){
    int m = bm + (ty<<2) + i;
    #pragma unroll
    for (int j=0;j<4;j++){
      int n = bn + (tx<<2) + j;
      float v = acc[i][j];
      if (BIAS) v += bias[n];
      if (RELU) v = fmaxf(v, 0.f);
      C[(size_t)m*N + n] = v;
    }
  }
}

// ---------- NN gemm (batched over l): T[l][b][d][k] = d_h @ U[l] ----------
__global__ __launch_bounds__(256)
void k_gemm_nn_T(const float* __restrict__ A, const float* __restrict__ U,
                 float* __restrict__ T){
  __shared__ float As[32][68];
  __shared__ float Bs[32][68];
  const int l = blockIdx.z;
  const float* Bm = U + (size_t)l*MLP*MLP;
  float* C = T + (size_t)l*NB*LD*MLP;
  const int bm = blockIdx.y*64, bn = blockIdx.x*64;
  const int tid = threadIdx.x;
  const int tx = tid & 15, ty = tid >> 4;
  const int lr = tid >> 3;
  const int lk = (tid & 7) << 2;
  const int bk_r = tid >> 4;
  const int bn_c = (tid & 15) << 2;
  const float* A0 = A + (size_t)(bm+lr)*MLP + lk;
  const float* A1 = A + (size_t)(bm+lr+32)*MLP + lk;
  float acc[4][4] = {};
  for (int k0=0;k0<MLP;k0+=32){
    float4 a0 = *(const float4*)(A0 + k0);
    float4 a1 = *(const float4*)(A1 + k0);
    float4 u0 = *(const float4*)(Bm + (size_t)(k0+bk_r)*MLP + bn + bn_c);
    float4 u1 = *(const float4*)(Bm + (size_t)(k0+bk_r+16)*MLP + bn + bn_c);
    __syncthreads();
    As[lk+0][lr]=a0.x; As[lk+1][lr]=a0.y; As[lk+2][lr]=a0.z; As[lk+3][lr]=a0.w;
    As[lk+0][lr+32]=a1.x; As[lk+1][lr+32]=a1.y; As[lk+2][lr+32]=a1.z; As[lk+3][lr+32]=a1.w;
    *(float4*)&Bs[bk_r][bn_c]    = u0;
    *(float4*)&Bs[bk_r+16][bn_c] = u1;
    __syncthreads();
    #pragma unroll
    for (int kk=0;kk<32;kk++){
      float4 av = *(const float4*)&As[kk][ty<<2];
      float4 bv = *(const float4*)&Bs[kk][tx<<2];
      float a4[4] = {av.x,av.y,av.z,av.w};
      float b4[4] = {bv.x,bv.y,bv.z,bv.w};
      #pragma unroll
      for (int i=0;i<4;i++)
        #pragma unroll
        for (int j=0;j<4;j++)
          acc[i][j] = fmaf(a4[i], b4[j], acc[i][j]);
    }
  }
  #pragma unroll
  for (int i=0;i<4;i++){
    int m = bm + (ty<<2) + i;
    #pragma unroll
    for (int j=0;j<4;j++)
      C[(size_t)m*MLP + bn + (tx<<2) + j] = acc[i][j];
  }
}

// -------- s_e / s_d: S[b][l][r] = dot(W[l], Hm[b,r,:]) --------
__global__ void k_bilinear(const float* __restrict__ W, const float* __restrict__ Hm,
                           float* __restrict__ S, int Lrows){
  int idx = blockIdx.x*256 + threadIdx.x;
  if (idx >= NB*Lrows) return;
  int b = idx / Lrows, r = idx - b*Lrows;
  const float* row = Hm + (size_t)idx*MLP;
  float acc[NL] = {0.f,0.f,0.f,0.f};
  for (int h=0; h<MLP; h+=4){
    float4 x = *(const float4*)(row + h);
    #pragma unroll
    for (int l=0;l<NL;l++){
      float4 w = *(const float4*)(W + l*MLP + h);
      acc[l] += x.x*w.x + x.y*w.y + x.z*w.z + x.w*w.w;
    }
  }
  #pragma unroll
  for (int l=0;l<NL;l++) S[((size_t)b*NL + l)*Lrows + r] = acc[l];
}

// -------- final: out[b,d,e,l] = T[l,b,d,:]·e_h[b,e,:] + s_d + s_e + b_aff --------
__global__ __launch_bounds__(256)
void k_s2(const float* __restrict__ T, const float* __restrict__ eh,
          const float* __restrict__ sd, const float* __restrict__ se,
          const float* __restrict__ baff, float* __restrict__ out){
  __shared__ float As[32][68];
  __shared__ float Bs[32][68];
  const int b = blockIdx.z;
  const int d0 = blockIdx.y*64, e0 = blockIdx.x*64;
  const int tid = threadIdx.x;
  const int tx = tid & 15, ty = tid >> 4;
  const int lr = tid >> 3;
  const int lk = (tid & 7) << 2;
  const float* EH = eh + (size_t)b*LE*MLP;
  for (int l=0;l<NL;l++){
    const float* A = T + ((size_t)(l*NB + b))*LD*MLP;
    float acc[4][4] = {};
    for (int k0=0;k0<MLP;k0+=32){
      float4 a0 = *(const float4*)(A + (size_t)(d0+lr)*MLP + k0 + lk);
      float4 a1 = *(const float4*)(A + (size_t)(d0+lr+32)*MLP + k0 + lk);
      float4 z4 = make_float4(0.f,0.f,0.f,0.f);
      int er0 = e0+lr, er1 = e0+lr+32;
      float4 b0 = (er0<LE) ? *(const float4*)(EH + (size_t)er0*MLP + k0 + lk) : z4;
      float4 b1 = (er1<LE) ? *(const float4*)(EH + (size_t)er1*MLP + k0 + lk) : z4;
      __syncthreads();
      As[lk+0][lr]=a0.x; As[lk+1][lr]=a0.y; As[lk+2][lr]=a0.z; As[lk+3][lr]=a0.w;
      As[lk+0][lr+32]=a1.x; As[lk+1][lr+32]=a1.y; As[lk+2][lr+32]=a1.z; As[lk+3][lr+32]=a1.w;
      Bs[lk+0][lr]=b0.x; Bs[lk+1][lr]=b0.y; Bs[lk+2][lr]=b0.z; Bs[lk+3][lr]=b0.w;
      Bs[lk+0][lr+32]=b1.x; Bs[lk+1][lr+32]=b1.y; Bs[lk+2][lr+32]=b1.z; Bs[lk+3][lr+32]=b1.w;
      __syncthreads();
      #pragma unroll
      for (int kk=0;kk<32;kk++){
        float4 av = *(const float4*)&As[kk][ty<<2];
        float4 bv = *(const float4*)&Bs[kk][tx<<2];
        float a4[4] = {av.x,av.y,av.z,av.w};
        float b4[4] = {bv.x,bv.y,bv.z,bv.w};
        #pragma unroll
        for (int i=0;i<4;i++)
          #pragma unroll
          for (int j=0;j<4;j++)
            acc[i][j] = fmaf(a4[i], b4[j], acc[i][j]);
      }
    }
    float bl = baff[l];
    float sdl[4], sel[4];
    #pragma unroll
    for (int i=0;i<4;i++) sdl[i] = sd[((size_t)b*NL + l)*LD + d0 + (ty<<2) + i];
    #pragma unroll
    for (int j=0;j<4;j++){
      int e = e0 + (tx<<2) + j;
      sel[j] = (e<LE) ? se[((size_t)b*NL + l)*LE + e] : 0.f;
    }
    #pragma unroll
    for (int i=0;i<4;i++){
      int d = d0 + (ty<<2) + i;
      #pragma unroll
      for (int j=0;j<4;j++){
        int e = e0 + (tx<<2) + j;
        if (e < LE)
          out[(((size_t)b*LD + d)*LE + e)*NL + l] = acc[i][j] + sdl[i] + sel[j] + bl;
      }
    }
  }
}

extern "C" void kernel_launch(void* const* d_in, const int* in_sizes, int n_in,
                              void* d_out, int out_size, void* d_ws, size_t ws_size,
                              hipStream_t stream){
  const float* e_outputs = (const float*)d_in[0];
  const float* d_inputs  = (const float*)d_in[1];
  const float* h0        = (const float*)d_in[2];
  const float* W_ih      = (const float*)d_in[3];
  const float* W_hh      = (const float*)d_in[4];
  const float* b_ih      = (const float*)d_in[5];
  const float* b_hh      = (const float*)d_in[6];
  const float* e_mlp_w   = (const float*)d_in[7];
  const float* e_mlp_b   = (const float*)d_in[8];
  const float* d_mlp_w   = (const float*)d_in[9];
  const float* d_mlp_b   = (const float*)d_in[10];
  const float* W_e       = (const float*)d_in[11];
  const float* W_d       = (const float*)d_in[12];
  const float* U         = (const float*)d_in[13];
  const float* b_aff     = (const float*)d_in[14];
  float* out = (float*)d_out;
  float* ws  = (float*)d_ws;

  // workspace layout (floats). T reuses GI's region (GI dead after k_gru).
  float* GI   = ws;                        // 32*256*1536 = 12,582,912
  float* T    = ws;                        // 4*32*256*256 = 8,388,608 (overlaps GI)
  float* hbuf = ws + 12582912;             // 2*32*512 = 32,768 f32 (double buffer)
  float* dout = ws   + 12582912 + 786432;  // 32*256*512 = 4,194,304
  float* eh   = dout + 4194304;            // 32*258*256 = 2,113,536
  float* dh   = eh   + 2113536;            // 32*256*256 = 2,097,152
  float* se   = dh   + 2097152;            // 32*4*258 = 33,024
  float* sd   = se   + 33024;              // 32*4*256 = 32,768

  k_init<<<dim3((2*NB*HID+255)/256), 256, 0, stream>>>((uint32_t*)hbuf);
  // GI = d_inputs @ W_ih^T + b_ih   (M=8192,N=1536,K=512)
  k_gemm_nt<1,0><<<dim3(H3/64, (NB*LD)/64), 256, 0, stream>>>(d_inputs, W_ih, b_ih, GI, NB*LD, H3, HID);
  // e_h = relu(e_outputs @ e_mlp_w^T + b)  (M=8256,N=256,K=512)
  k_gemm_nt<1,1><<<dim3(MLP/64, (NB*LE)/64), 256, 0, stream>>>(e_outputs, e_mlp_w, e_mlp_b, eh, NB*LE, MLP, HID);
  // GRU recurrence -> d_outputs (8 slices/batch, tagged-payload sync)
  k_gru<<<dim3(NB*8), 192, 0, stream>>>(GI, W_hh, b_hh, h0, dout, hbuf);
  // d_h = relu(d_outputs @ d_mlp_w^T + b)  (M=8192,N=256,K=512)
  k_gemm_nt<1,1><<<dim3(MLP/64, (NB*LD)/64), 256, 0, stream>>>(dout, d_mlp_w, d_mlp_b, dh, NB*LD, MLP, HID);
  // T[l] = d_h @ U[l]  (M=8192,N=256,K=256, batched over l)
  k_gemm_nn_T<<<dim3(MLP/64, (NB*LD)/64, NL), 256, 0, stream>>>(dh, U, T);
  // s_e, s_d
  k_bilinear<<<dim3((NB*LE+255)/256), 256, 0, stream>>>(W_e, eh, se, LE);
  k_bilinear<<<dim3((NB*LD+255)/256), 256, 0, stream>>>(W_d, dh, sd, LD);
  // out[b,d,e,l] = T[l,b,d,:]·e_h[b,e,:] + s_d + s_e + b_aff
  k_s2<<<dim3(5, LD/64, NB), 256, 0, stream>>>(T, eh, sd, se, b_aff, out);
}